// Round 4
// baseline (285.649 us; speedup 1.0000x reference)
//
#include <hip/hip_runtime.h>
#include <math.h>

// Problem constants (B=4, H=W=128, C=256, 2x2 pool, VALID)
#define NT4   1048576                // float4 groups per output tensor
#define NELEM ((size_t)NT4 * 4)      // 4,194,304 floats per output tensor
#define GRID  4096                   // one float4 tile per thread, no loop

typedef float vf4 __attribute__((ext_vector_type(4)));

// ---- float atomic min/max via int-representation monotone trick ----
__device__ __forceinline__ void atomicMaxF(float* addr, float val) {
    if (val >= 0.0f) atomicMax((int*)addr, __float_as_int(val));
    else             atomicMin((unsigned int*)addr, __float_as_uint(val));
}
__device__ __forceinline__ void atomicMinF(float* addr, float val) {
    if (val >= 0.0f) atomicMin((int*)addr, __float_as_int(val));
    else             atomicMax((unsigned int*)addr, __float_as_uint(val));
}

__global__ void init_kernel(const float* __restrict__ l_in,
                            const float* __restrict__ u_in,
                            float* __restrict__ out) {
    out[4 * NELEM]     = l_in[0];
    out[4 * NELEM + 1] = u_in[0];
}

// input float4 index of window corner (ph=0, pw=0) for tile gi
// gi = ((b*64 + hp)*64 + wp)*64 + c4
__device__ __forceinline__ int baseof(int gi) {
    return (((gi >> 18) * 128 + 2 * ((gi >> 12) & 63)) * 128
            + 2 * ((gi >> 6) & 63)) * 64 + (gi & 63);
}

__global__ __launch_bounds__(256) void maxpool_kernel(
    const vf4* __restrict__ x,  const vf4* __restrict__ bias,
    const vf4* __restrict__ a,  const vf4* __restrict__ bt,
    float* __restrict__ out)
{
    const int gi   = blockIdx.x * 256 + threadIdx.x;  // one output tile
    const int base = baseof(gi);

    // window slots in float4 units: +0 (0,0), +64 (0,1), +8192 (1,0), +8256 (1,1)
    // Plain loads: let the compiler pick addressing modes and waitcnt placement.
    vf4 X[4], Bv[4], A[4], Ct[4];
#pragma unroll
    for (int j = 0; j < 4; ++j) {
        const int o = ((j & 2) ? 8192 : 0) + ((j & 1) ? 64 : 0);
        X[j]  = x[base + o];
        Bv[j] = bias[base + o];
        A[j]  = a[base + o];
        Ct[j] = bt[base + o];
    }

    float lmax = -INFINITY, umin = INFINITY;
    vf4 rx, rb, ra, rc;
#pragma unroll
    for (int c = 0; c < 4; ++c) {
        float xw[4], bw[4], aw[4], cw[4];
#pragma unroll
        for (int j = 0; j < 4; ++j) {
            xw[j] = X[j][c];  bw[j] = Bv[j][c];
            aw[j] = A[j][c];  cw[j] = Ct[j][c];
        }
        // first-occurrence argmax (strict >) with fused gather of the other 3
        float sx = xw[0], sb = bw[0], sa = aw[0], sc = cw[0];
#pragma unroll
        for (int j = 1; j < 4; ++j) {
            bool gt = xw[j] > sx;
            sx = gt ? xw[j] : sx;
            sb = gt ? bw[j] : sb;
            sa = gt ? aw[j] : sa;
            sc = gt ? cw[j] : sc;
        }
        rx[c] = sx; rb[c] = sb; ra[c] = sa; rc[c] = sc;
        // truncated interval over the 4 window entries
#pragma unroll
        for (int j = 0; j < 4; ++j) {
            float tb  = cw[j] - sc;
            float nom = -((aw[j] - sa) + (bw[j] - sb));
            float q   = nom / tb;            // consumed only when tb != 0
            if (tb > 0.0f)      umin = fminf(umin, q);
            else if (tb < 0.0f) lmax = fmaxf(lmax, q);
        }
    }
    ((vf4*)out)[gi]               = rx;
    ((vf4*)(out + NELEM))[gi]     = rb;
    ((vf4*)(out + 2 * NELEM))[gi] = ra;
    ((vf4*)(out + 3 * NELEM))[gi] = rc;

    // ---- block reduction of (lmax, umin), once per block ----
#pragma unroll
    for (int s = 32; s; s >>= 1) {
        lmax = fmaxf(lmax, __shfl_down(lmax, s, 64));
        umin = fminf(umin, __shfl_down(umin, s, 64));
    }
    __shared__ float sl[4], su[4];
    const int wave = threadIdx.x >> 6;
    if ((threadIdx.x & 63) == 0) { sl[wave] = lmax; su[wave] = umin; }
    __syncthreads();
    if (threadIdx.x == 0) {
        float ll = fmaxf(fmaxf(sl[0], sl[1]), fmaxf(sl[2], sl[3]));
        float uu = fminf(fminf(su[0], su[1]), fminf(su[2], su[3]));
        atomicMaxF(&out[4 * NELEM],     ll);
        atomicMinF(&out[4 * NELEM + 1], uu);
    }
}

extern "C" void kernel_launch(void* const* d_in, const int* in_sizes, int n_in,
                              void* d_out, int out_size, void* d_ws, size_t ws_size,
                              hipStream_t stream) {
    const vf4* x    = (const vf4*)d_in[0];
    const vf4* bias = (const vf4*)d_in[1];
    const vf4* a    = (const vf4*)d_in[2];
    const vf4* bt   = (const vf4*)d_in[3];
    const float* l_in = (const float*)d_in[4];
    const float* u_in = (const float*)d_in[5];
    float* out = (float*)d_out;

    init_kernel<<<1, 1, 0, stream>>>(l_in, u_in, out);
    maxpool_kernel<<<GRID, 256, 0, stream>>>(x, bias, a, bt, out);
}

// Round 5
// 255.818 us; speedup vs baseline: 1.1166x; 1.1166x over previous
//
#include <hip/hip_runtime.h>
#include <math.h>

// Problem constants (B=4, H=W=128, C=256, 2x2 pool, VALID)
#define NT4   1048576                // float4 groups per output tensor
#define NELEM ((size_t)NT4 * 4)      // 4,194,304 floats per output tensor
#define GRID  512
#define ITERS 8                      // NT4 / (GRID*256)
#define STEP  (GRID * 256)           // 131072 tiles per grid pass

typedef float vf4 __attribute__((ext_vector_type(4)));

// ---- float atomic min/max via int-representation monotone trick ----
__device__ __forceinline__ void atomicMaxF(float* addr, float val) {
    if (val >= 0.0f) atomicMax((int*)addr, __float_as_int(val));
    else             atomicMin((unsigned int*)addr, __float_as_uint(val));
}
__device__ __forceinline__ void atomicMinF(float* addr, float val) {
    if (val >= 0.0f) atomicMin((int*)addr, __float_as_int(val));
    else             atomicMax((unsigned int*)addr, __float_as_uint(val));
}

__global__ void init_kernel(const float* __restrict__ l_in,
                            const float* __restrict__ u_in,
                            float* __restrict__ out) {
    out[4 * NELEM]     = l_in[0];
    out[4 * NELEM + 1] = u_in[0];
}

// Hand-issued 16B loads, NON-TEMPORAL (`nt`): streaming/no-allocate hint.
// Inputs are read exactly once per iteration — allocating them through
// L2/L3 only churns tags and victim writebacks (the suspected 2x BW loss).
#define GLOAD(dst, ptr) \
    asm volatile("global_load_dwordx4 %0, %1, off nt" : "=v"(dst) : "v"(ptr))
#define GLOAD_OFS(dst, ptr) \
    asm volatile("global_load_dwordx4 %0, %1, off offset:1024 nt" : "=v"(dst) : "v"(ptr))

// input float4 index of window corner (ph=0, pw=0) for tile gi
__device__ __forceinline__ int baseof(int gi) {
    return (((gi >> 18) * 128 + 2 * ((gi >> 12) & 63)) * 128
            + 2 * ((gi >> 6) & 63)) * 64 + (gi & 63);
}

// issue 16 loads (one tile, 4 tensors x 4 window slots), no wait
#define LOAD_SET(X, Bv, A, Ct, gi) do {                                     \
    const int base_ = baseof(gi);                                           \
    const vf4* px_ = x    + base_;  const vf4* pb_ = bias + base_;          \
    const vf4* pa_ = a    + base_;  const vf4* pc_ = bt   + base_;          \
    GLOAD(X[0],  px_); GLOAD_OFS(X[1],  px_);                               \
    GLOAD(X[2],  px_ + 8192); GLOAD_OFS(X[3],  px_ + 8192);                 \
    GLOAD(Bv[0], pb_); GLOAD_OFS(Bv[1], pb_);                               \
    GLOAD(Bv[2], pb_ + 8192); GLOAD_OFS(Bv[3], pb_ + 8192);                 \
    GLOAD(A[0],  pa_); GLOAD_OFS(A[1],  pa_);                               \
    GLOAD(A[2],  pa_ + 8192); GLOAD_OFS(A[3],  pa_ + 8192);                 \
    GLOAD(Ct[0], pc_); GLOAD_OFS(Ct[1], pc_);                               \
    GLOAD(Ct[2], pc_ + 8192); GLOAD_OFS(Ct[3], pc_ + 8192);                 \
} while (0)

// wait until only the N newest vmem ops remain outstanding; pins this set's
// 16 results so consumers can't hoist above and the loads can't sink below.
// N accounts for BOTH newer loads and newer stores (vmcnt counts stores).
#define WAIT_SET(N, X, Bv, A, Ct)                                           \
    asm volatile("s_waitcnt vmcnt(" #N ")"                                  \
                 : "+v"(X[0]),  "+v"(X[1]),  "+v"(X[2]),  "+v"(X[3]),       \
                   "+v"(Bv[0]), "+v"(Bv[1]), "+v"(Bv[2]), "+v"(Bv[3]),      \
                   "+v"(A[0]),  "+v"(A[1]),  "+v"(A[2]),  "+v"(A[3]),       \
                   "+v"(Ct[0]), "+v"(Ct[1]), "+v"(Ct[2]), "+v"(Ct[3])       \
                 :: "memory")

__device__ __forceinline__ void process_tile(
    const vf4 (&X)[4], const vf4 (&Bv)[4], const vf4 (&A)[4], const vf4 (&Ct)[4],
    int gi, float* __restrict__ out, float& lmax, float& umin)
{
    vf4 rx, rb, ra, rc;
#pragma unroll
    for (int c = 0; c < 4; ++c) {
        float xw[4], bw[4], aw[4], cw[4];
#pragma unroll
        for (int j = 0; j < 4; ++j) {
            xw[j] = X[j][c];  bw[j] = Bv[j][c];
            aw[j] = A[j][c];  cw[j] = Ct[j][c];
        }
        // first-occurrence argmax (strict >) with fused gather of the other 3
        float sx = xw[0], sb = bw[0], sa = aw[0], sc = cw[0];
#pragma unroll
        for (int j = 1; j < 4; ++j) {
            bool gt = xw[j] > sx;
            sx = gt ? xw[j] : sx;
            sb = gt ? bw[j] : sb;
            sa = gt ? aw[j] : sa;
            sc = gt ? cw[j] : sc;
        }
        rx[c] = sx; rb[c] = sb; ra[c] = sa; rc[c] = sc;
        // truncated interval over the 4 window entries
#pragma unroll
        for (int j = 0; j < 4; ++j) {
            float tb  = cw[j] - sc;
            float nom = -((aw[j] - sa) + (bw[j] - sb));
            float q   = nom / tb;            // consumed only when tb != 0
            if (tb > 0.0f)      umin = fminf(umin, q);
            else if (tb < 0.0f) lmax = fmaxf(lmax, q);
        }
    }
    // Non-temporal stores: write-once data, never re-read by this kernel.
    __builtin_nontemporal_store(rx, (vf4*)out + gi);
    __builtin_nontemporal_store(rb, (vf4*)(out + NELEM) + gi);
    __builtin_nontemporal_store(ra, (vf4*)(out + 2 * NELEM) + gi);
    __builtin_nontemporal_store(rc, (vf4*)(out + 3 * NELEM) + gi);
}

__global__ __launch_bounds__(256) void maxpool_kernel(
    const vf4* __restrict__ x,  const vf4* __restrict__ bias,
    const vf4* __restrict__ a,  const vf4* __restrict__ bt,
    float* __restrict__ out)
{
    const int g = blockIdx.x * 256 + threadIdx.x;   // first tile of this thread

    vf4 XA[4], BA[4], AA[4], CA[4];
    vf4 XB[4], BB[4], AB[4], CB[4];
    float lmax = -INFINITY, umin = INFINITY;

    // persistent double-buffered stream: the 16 newest loads are ALWAYS in
    // flight while the previous tile computes.
    // Steady-state wait: [prev-set loads 16][prev stores 4][next loads 16]
    // outstanding => prev-set complete <=> vmcnt <= 20 (don't wait on store acks).
    LOAD_SET(XA, BA, AA, CA, g);
#pragma unroll
    for (int it = 0; it < ITERS; it += 2) {
        const int gA = g + it * STEP, gB = gA + STEP, gC = gA + 2 * STEP;
        LOAD_SET(XB, BB, AB, CB, gB);
        if (it == 0) { WAIT_SET(16, XA, BA, AA, CA); }   // no stores yet
        else         { WAIT_SET(20, XA, BA, AA, CA); }
        process_tile(XA, BA, AA, CA, gA, out, lmax, umin);
        if (it + 2 < ITERS) {
            LOAD_SET(XA, BA, AA, CA, gC);
            WAIT_SET(20, XB, BB, AB, CB);
        } else {
            // only [B loads 16][A stores 4] remain; drain B, leave stores
            WAIT_SET(4, XB, BB, AB, CB);
        }
        process_tile(XB, BB, AB, CB, gB, out, lmax, umin);
    }

    // ---- block reduction of (lmax, umin), once per block ----
#pragma unroll
    for (int s = 32; s; s >>= 1) {
        lmax = fmaxf(lmax, __shfl_down(lmax, s, 64));
        umin = fminf(umin, __shfl_down(umin, s, 64));
    }
    __shared__ float sl[4], su[4];
    const int wave = threadIdx.x >> 6;
    if ((threadIdx.x & 63) == 0) { sl[wave] = lmax; su[wave] = umin; }
    __syncthreads();
    if (threadIdx.x == 0) {
        float ll = fmaxf(fmaxf(sl[0], sl[1]), fmaxf(sl[2], sl[3]));
        float uu = fminf(fminf(su[0], su[1]), fminf(su[2], su[3]));
        atomicMaxF(&out[4 * NELEM],     ll);
        atomicMinF(&out[4 * NELEM + 1], uu);
    }
}

extern "C" void kernel_launch(void* const* d_in, const int* in_sizes, int n_in,
                              void* d_out, int out_size, void* d_ws, size_t ws_size,
                              hipStream_t stream) {
    const vf4* x    = (const vf4*)d_in[0];
    const vf4* bias = (const vf4*)d_in[1];
    const vf4* a    = (const vf4*)d_in[2];
    const vf4* bt   = (const vf4*)d_in[3];
    const float* l_in = (const float*)d_in[4];
    const float* u_in = (const float*)d_in[5];
    float* out = (float*)d_out;

    init_kernel<<<1, 1, 0, stream>>>(l_in, u_in, out);
    maxpool_kernel<<<GRID, 256, 0, stream>>>(x, bias, a, bt, out);
}

// Round 6
// 252.944 us; speedup vs baseline: 1.1293x; 1.0114x over previous
//
#include <hip/hip_runtime.h>
#include <math.h>

// Problem constants (B=4, H=W=128, C=256, 2x2 pool, VALID)
// float2 quantum: halves per-wave pinned VGPRs (2 sets x 16 x 2 = 64) so
// 4 blocks/CU co-reside cleanly -> 16 waves/CU issuing nt loads.
#define NT2   2097152                // float2 groups per output tensor
#define NELEM ((size_t)NT2 * 2)     // 4,194,304 floats per output tensor
#define GRID  1024                  // 4 blocks/CU
#define ITERS 8                     // NT2 / (GRID*256)
#define STEP  (GRID * 256)          // 262144 tiles per grid pass

typedef float vf2 __attribute__((ext_vector_type(2)));

// ---- float atomic min/max via int-representation monotone trick ----
__device__ __forceinline__ void atomicMaxF(float* addr, float val) {
    if (val >= 0.0f) atomicMax((int*)addr, __float_as_int(val));
    else             atomicMin((unsigned int*)addr, __float_as_uint(val));
}
__device__ __forceinline__ void atomicMinF(float* addr, float val) {
    if (val >= 0.0f) atomicMin((int*)addr, __float_as_int(val));
    else             atomicMax((unsigned int*)addr, __float_as_uint(val));
}

__global__ void init_kernel(const float* __restrict__ l_in,
                            const float* __restrict__ u_in,
                            float* __restrict__ out) {
    out[4 * NELEM]     = l_in[0];
    out[4 * NELEM + 1] = u_in[0];
}

// Hand-issued 8B loads, NON-TEMPORAL: no L2 allocation for stream-once data
// (the r5-verified +29% mechanism).
#define GLOAD(dst, ptr) \
    asm volatile("global_load_dwordx2 %0, %1, off nt" : "=v"(dst) : "v"(ptr))
#define GLOAD_OFS(dst, ptr) \
    asm volatile("global_load_dwordx2 %0, %1, off offset:1024 nt" : "=v"(dst) : "v"(ptr))

// input float2 index of window corner (ph=0, pw=0) for tile gi
// gi = ((b*64 + hp)*64 + wp)*128 + c2  (c2 = channel-pair index)
__device__ __forceinline__ int baseof(int gi) {
    return (((gi >> 19) * 128 + 2 * ((gi >> 13) & 63)) * 128
            + 2 * ((gi >> 7) & 63)) * 128 + (gi & 127);
}

// issue 16 loads (one tile, 4 tensors x 4 window slots), no wait
// window slots in float2 units: +0, +128 (offset:1024B), +16384 (next row), +16384+128
#define LOAD_SET(X, Bv, A, Ct, gi) do {                                     \
    const int base_ = baseof(gi);                                           \
    const vf2* px_ = x    + base_;  const vf2* pb_ = bias + base_;          \
    const vf2* pa_ = a    + base_;  const vf2* pc_ = bt   + base_;          \
    GLOAD(X[0],  px_); GLOAD_OFS(X[1],  px_);                               \
    GLOAD(X[2],  px_ + 16384); GLOAD_OFS(X[3],  px_ + 16384);               \
    GLOAD(Bv[0], pb_); GLOAD_OFS(Bv[1], pb_);                               \
    GLOAD(Bv[2], pb_ + 16384); GLOAD_OFS(Bv[3], pb_ + 16384);               \
    GLOAD(A[0],  pa_); GLOAD_OFS(A[1],  pa_);                               \
    GLOAD(A[2],  pa_ + 16384); GLOAD_OFS(A[3],  pa_ + 16384);               \
    GLOAD(Ct[0], pc_); GLOAD_OFS(Ct[1], pc_);                               \
    GLOAD(Ct[2], pc_ + 16384); GLOAD_OFS(Ct[3], pc_ + 16384);               \
} while (0)

// wait until only the N newest vmem ops remain outstanding; pins this set's
// 16 results. N counts newer loads AND newer stores (vmcnt counts stores).
#define WAIT_SET(N, X, Bv, A, Ct)                                           \
    asm volatile("s_waitcnt vmcnt(" #N ")"                                  \
                 : "+v"(X[0]),  "+v"(X[1]),  "+v"(X[2]),  "+v"(X[3]),       \
                   "+v"(Bv[0]), "+v"(Bv[1]), "+v"(Bv[2]), "+v"(Bv[3]),      \
                   "+v"(A[0]),  "+v"(A[1]),  "+v"(A[2]),  "+v"(A[3]),       \
                   "+v"(Ct[0]), "+v"(Ct[1]), "+v"(Ct[2]), "+v"(Ct[3])       \
                 :: "memory")

__device__ __forceinline__ void process_tile(
    const vf2 (&X)[4], const vf2 (&Bv)[4], const vf2 (&A)[4], const vf2 (&Ct)[4],
    int gi, float* __restrict__ out, float& lmax, float& umin)
{
    vf2 rx, rb, ra, rc;
#pragma unroll
    for (int c = 0; c < 2; ++c) {
        float xw[4], bw[4], aw[4], cw[4];
#pragma unroll
        for (int j = 0; j < 4; ++j) {
            xw[j] = X[j][c];  bw[j] = Bv[j][c];
            aw[j] = A[j][c];  cw[j] = Ct[j][c];
        }
        // first-occurrence argmax (strict >) with fused gather of the other 3
        float sx = xw[0], sb = bw[0], sa = aw[0], sc = cw[0];
#pragma unroll
        for (int j = 1; j < 4; ++j) {
            bool gt = xw[j] > sx;
            sx = gt ? xw[j] : sx;
            sb = gt ? bw[j] : sb;
            sa = gt ? aw[j] : sa;
            sc = gt ? cw[j] : sc;
        }
        rx[c] = sx; rb[c] = sb; ra[c] = sa; rc[c] = sc;
        // truncated interval over the 4 window entries
#pragma unroll
        for (int j = 0; j < 4; ++j) {
            float tb  = cw[j] - sc;
            float nom = -((aw[j] - sa) + (bw[j] - sb));
            float q   = nom / tb;            // consumed only when tb != 0
            if (tb > 0.0f)      umin = fminf(umin, q);
            else if (tb < 0.0f) lmax = fmaxf(lmax, q);
        }
    }
    // Non-temporal stores: write-once data, never re-read by this kernel.
    __builtin_nontemporal_store(rx, (vf2*)out + gi);
    __builtin_nontemporal_store(rb, (vf2*)(out + NELEM) + gi);
    __builtin_nontemporal_store(ra, (vf2*)(out + 2 * NELEM) + gi);
    __builtin_nontemporal_store(rc, (vf2*)(out + 3 * NELEM) + gi);
}

__global__ __launch_bounds__(256) void maxpool_kernel(
    const vf2* __restrict__ x,  const vf2* __restrict__ bias,
    const vf2* __restrict__ a,  const vf2* __restrict__ bt,
    float* __restrict__ out)
{
    const int g = blockIdx.x * 256 + threadIdx.x;   // first tile of this thread

    vf2 XA[4], BA[4], AA[4], CA[4];
    vf2 XB[4], BB[4], AB[4], CB[4];
    float lmax = -INFINITY, umin = INFINITY;

    // persistent double-buffered stream; store-aware wait accounting:
    // steady state outstanding at wait = [prev 16 loads][4 stores][16 loads]
    // -> prev set complete <=> vmcnt <= 20 (never gate on store-acks).
    LOAD_SET(XA, BA, AA, CA, g);
#pragma unroll
    for (int it = 0; it < ITERS; it += 2) {
        const int gA = g + it * STEP, gB = gA + STEP, gC = gA + 2 * STEP;
        LOAD_SET(XB, BB, AB, CB, gB);
        if (it == 0) { WAIT_SET(16, XA, BA, AA, CA); }   // no stores yet
        else         { WAIT_SET(20, XA, BA, AA, CA); }
        process_tile(XA, BA, AA, CA, gA, out, lmax, umin);
        if (it + 2 < ITERS) {
            LOAD_SET(XA, BA, AA, CA, gC);
            WAIT_SET(20, XB, BB, AB, CB);
        } else {
            // only [B loads 16][A stores 4] remain; drain B, leave stores
            WAIT_SET(4, XB, BB, AB, CB);
        }
        process_tile(XB, BB, AB, CB, gB, out, lmax, umin);
    }

    // ---- block reduction of (lmax, umin), once per block ----
#pragma unroll
    for (int s = 32; s; s >>= 1) {
        lmax = fmaxf(lmax, __shfl_down(lmax, s, 64));
        umin = fminf(umin, __shfl_down(umin, s, 64));
    }
    __shared__ float sl[4], su[4];
    const int wave = threadIdx.x >> 6;
    if ((threadIdx.x & 63) == 0) { sl[wave] = lmax; su[wave] = umin; }
    __syncthreads();
    if (threadIdx.x == 0) {
        float ll = fmaxf(fmaxf(sl[0], sl[1]), fmaxf(sl[2], sl[3]));
        float uu = fminf(fminf(su[0], su[1]), fminf(su[2], su[3]));
        atomicMaxF(&out[4 * NELEM],     ll);
        atomicMinF(&out[4 * NELEM + 1], uu);
    }
}

extern "C" void kernel_launch(void* const* d_in, const int* in_sizes, int n_in,
                              void* d_out, int out_size, void* d_ws, size_t ws_size,
                              hipStream_t stream) {
    const vf2* x    = (const vf2*)d_in[0];
    const vf2* bias = (const vf2*)d_in[1];
    const vf2* a    = (const vf2*)d_in[2];
    const vf2* bt   = (const vf2*)d_in[3];
    const float* l_in = (const float*)d_in[4];
    const float* u_in = (const float*)d_in[5];
    float* out = (float*)d_out;

    init_kernel<<<1, 1, 0, stream>>>(l_in, u_in, out);
    maxpool_kernel<<<GRID, 256, 0, stream>>>(x, bias, a, bt, out);
}